// Round 4
// baseline (551.838 us; speedup 1.0000x reference)
//
#include <hip/hip_runtime.h>

// B=4, S=4096, H=512, K=2, D=8, experts=64
// T = 16384 tokens; out: [8, 32768, 512] fp32 = 512 MiB
#define NDEV     8
#define TOK      16384
#define TKROWS   (TOK * 2)            // 32768 (token,k) rows
#define COLS     128                  // float4 per row (H=512)
#define DSTRIDE  (TKROWS * COLS)      // float4 elems per device section
#define TOTAL4   (TKROWS * COLS)      // 4,194,304 (tk,col) positions

#define BLOCKS   1024
#define THREADS  256
#define PERTHR   (TOTAL4 / (BLOCKS * THREADS))   // 16 iterations

typedef float f4 __attribute__((ext_vector_type(4)));

// Persistent grid-stride fused kernel: each thread streams through a
// contiguous 2 KiB segment of (tk,col) space, writing all 8 device slots
// per position (one token value, seven zeros). Long-lived waves amortize
// setup and keep the store pipe saturated like the rocclr fill kernel.
__global__ __launch_bounds__(THREADS)
void a2a_fused_kernel(const f4*  __restrict__ x,     // [TOK, COLS]
                      const int* __restrict__ eidx,  // [TKROWS]
                      const int* __restrict__ emap,  // [64]
                      f4*        __restrict__ out)   // [NDEV, TKROWS, COLS]
{
    const int seg = blockIdx.x * (THREADS * PERTHR);   // block-contiguous segment
    const f4 z = {0.f, 0.f, 0.f, 0.f};

#pragma unroll 4
    for (int i = 0; i < PERTHR; ++i) {
        const int idx = seg + i * THREADS + threadIdx.x;  // < TOTAL4
        const int col = idx & (COLS - 1);
        const int tk  = idx >> 7;
        const int t   = tk >> 1;                          // token id (K=2)

        // tk is wave-uniform (64 consecutive idx, 64-aligned, 128 cols/row).
        // Force it scalar so the index chain becomes s_load + scalar compare.
        const int tk_s = __builtin_amdgcn_readfirstlane(tk);
        const int dev  = emap[eidx[tk_s]];                // in [0, NDEV)

        const f4 v = x[t * COLS + col];

#pragma unroll
        for (int d = 0; d < NDEV; ++d) {
            out[(size_t)d * DSTRIDE + idx] = (d == dev) ? v : z;
        }
    }
}

extern "C" void kernel_launch(void* const* d_in, const int* in_sizes, int n_in,
                              void* d_out, int out_size, void* d_ws, size_t ws_size,
                              hipStream_t stream) {
    const f4*  x    = (const f4*)d_in[0];
    const int* eidx = (const int*)d_in[1];
    const int* emap = (const int*)d_in[2];
    f4*        out  = (f4*)d_out;

    a2a_fused_kernel<<<BLOCKS, THREADS, 0, stream>>>(x, eidx, emap, out);
}